// Round 2
// baseline (1806.499 us; speedup 1.0000x reference)
//
#include <hip/hip_runtime.h>
#include <math.h>

#define D 512
#define S 128
#define NB 256   // N = A*B
#define T132 132 // S + L - 1

static inline __device__ float4 ld4(const float* p) { return *(const float4*)p; }

// ---------------------------------------------------------------------------
// GEMM: out[m, o] = sum_d src(m)[d] * W[o][d] + bias[o]
// src(m): row gather over concat(pad, x) per n (padRows leading pad rows).
// Tile 64x64, 256 threads, 4x4 acc/thread, k-chunk 16, transposed LDS tiles.
// ---------------------------------------------------------------------------
__global__ __launch_bounds__(256) void gemm_rowgather(
    const float* __restrict__ x, const float* __restrict__ pad,
    const float* __restrict__ W, const float* __restrict__ bias,
    float* __restrict__ out, int rowsPerN, int padRows)
{
    __shared__ float XsT[16][68];
    __shared__ float WsT[16][68];
    const int t  = threadIdx.x;
    const int ty = t >> 4, tx = t & 15;
    const int blockRow = blockIdx.x * 64;
    const int blockCol = blockIdx.y * 64;
    const int lrow = t >> 2;          // 0..63
    const int lk   = (t & 3) * 4;     // 0,4,8,12

    int m = blockRow + lrow;
    int n = m / rowsPerN;
    int r = m - n * rowsPerN;
    const float* src = (r < padRows)
        ? (pad + ((size_t)(n * padRows + r)) * D)
        : (x   + ((size_t)(n * S + (r - padRows))) * D);
    const float* wrow = W + (size_t)(blockCol + lrow) * D;

    float acc[4][4] = {};
    for (int k0 = 0; k0 < D; k0 += 16) {
        float4 xa = ld4(src  + k0 + lk);
        float4 wa = ld4(wrow + k0 + lk);
        __syncthreads();
        XsT[lk+0][lrow] = xa.x; XsT[lk+1][lrow] = xa.y;
        XsT[lk+2][lrow] = xa.z; XsT[lk+3][lrow] = xa.w;
        WsT[lk+0][lrow] = wa.x; WsT[lk+1][lrow] = wa.y;
        WsT[lk+2][lrow] = wa.z; WsT[lk+3][lrow] = wa.w;
        __syncthreads();
#pragma unroll
        for (int kk = 0; kk < 16; ++kk) {
            float4 av = *(const float4*)&XsT[kk][ty * 4];
            float4 bv = *(const float4*)&WsT[kk][tx * 4];
            acc[0][0] += av.x*bv.x; acc[0][1] += av.x*bv.y; acc[0][2] += av.x*bv.z; acc[0][3] += av.x*bv.w;
            acc[1][0] += av.y*bv.x; acc[1][1] += av.y*bv.y; acc[1][2] += av.y*bv.z; acc[1][3] += av.y*bv.w;
            acc[2][0] += av.z*bv.x; acc[2][1] += av.z*bv.y; acc[2][2] += av.z*bv.z; acc[2][3] += av.z*bv.w;
            acc[3][0] += av.w*bv.x; acc[3][1] += av.w*bv.y; acc[3][2] += av.w*bv.z; acc[3][3] += av.w*bv.w;
        }
    }
    float4 bb = ld4(bias + blockCol + tx * 4);
#pragma unroll
    for (int i = 0; i < 4; ++i) {
        float4 o;
        o.x = acc[i][0] + bb.x; o.y = acc[i][1] + bb.y;
        o.z = acc[i][2] + bb.z; o.w = acc[i][3] + bb.w;
        *(float4*)(out + (size_t)(blockRow + ty*4 + i) * D + blockCol + tx*4) = o;
    }
}

// ---------------------------------------------------------------------------
// Window softmax weights: one wave per (n, s). y: [N][132][D].
// scores_l = dot(y[s+4], y[s+l]) / sqrt(512); softmax over l; write 5 weights.
// ---------------------------------------------------------------------------
__global__ __launch_bounds__(256) void win_weights(const float* __restrict__ y,
                                                   float* __restrict__ wbuf)
{
    int g = blockIdx.x * 256 + threadIdx.x;
    int wv = g >> 6, lane = g & 63;
    int n = wv >> 7, s = wv & 127;
    const float* base = y + ((size_t)(n * T132 + s)) * D;
    float4 c0 = ld4(base + 4*D + lane*4);
    float4 c1 = ld4(base + 4*D + 256 + lane*4);
    float sc[5];
#pragma unroll
    for (int j = 0; j < 5; ++j) {
        float4 a0 = ld4(base + j*D + lane*4);
        float4 a1 = ld4(base + j*D + 256 + lane*4);
        float p = c0.x*a0.x + c0.y*a0.y + c0.z*a0.z + c0.w*a0.w
                + c1.x*a1.x + c1.y*a1.y + c1.z*a1.z + c1.w*a1.w;
#pragma unroll
        for (int off = 1; off < 64; off <<= 1) p += __shfl_xor(p, off);
        sc[j] = p * 0.044194173824159216f;   // 1/sqrt(512)
    }
    if (lane == 0) {
        float mx = sc[0];
#pragma unroll
        for (int j = 1; j < 5; ++j) mx = fmaxf(mx, sc[j]);
        float e[5], sum = 0.f;
#pragma unroll
        for (int j = 0; j < 5; ++j) { e[j] = expf(sc[j] - mx); sum += e[j]; }
        float inv = 1.f / sum;
        float* wp = wbuf + ((size_t)(n * 128 + s)) * 5;
#pragma unroll
        for (int j = 0; j < 5; ++j) wp[j] = e[j] * inv;
    }
}

// ---------------------------------------------------------------------------
// Scrambled window combine (reference's reshape (S,L)->(L,S)):
// out[n,s2,:] = sum_{l2<5} w[n, f/5, f%5] * y[n, f/5 + f%5, :],  f = l2*128+s2
// ---------------------------------------------------------------------------
__global__ __launch_bounds__(256) void win_combine(const float* __restrict__ y,
                                                   const float* __restrict__ wbuf,
                                                   float* __restrict__ outq)
{
    int g = blockIdx.x * 256 + threadIdx.x;
    int wv = g >> 6, lane = g & 63;
    int n = wv >> 7, s2 = wv & 127;
    float4 a0 = {0,0,0,0}, a1 = {0,0,0,0};
#pragma unroll
    for (int l2 = 0; l2 < 5; ++l2) {
        int f = l2 * 128 + s2;
        int sidx = f / 5;
        int l = f - sidx * 5;
        float wt = wbuf[((size_t)(n * 128 + sidx)) * 5 + l];
        const float* r = y + ((size_t)(n * T132 + sidx + l)) * D;
        float4 v0 = ld4(r + lane*4), v1 = ld4(r + 256 + lane*4);
        a0.x += wt*v0.x; a0.y += wt*v0.y; a0.z += wt*v0.z; a0.w += wt*v0.w;
        a1.x += wt*v1.x; a1.y += wt*v1.y; a1.z += wt*v1.z; a1.w += wt*v1.w;
    }
    float* op = outq + ((size_t)(n * 128 + s2)) * D;
    *(float4*)(op + lane*4) = a0;
    *(float4*)(op + 256 + lane*4) = a1;
}

// ---------------------------------------------------------------------------
// Attention 1: per (n,h), S=128 keys, dk=64. One q-row per thread (128 thr).
// K,V staged in LDS (64 KB). Two-pass softmax (max pass + exp/accumulate).
// NOTE: x1 may alias v — all global reads of v happen during staging (before
// __syncthreads); the (n,h) slice written is touched by no other block.
// ---------------------------------------------------------------------------
__global__ __launch_bounds__(128) void attn1_kernel(const float* __restrict__ q,
                                                    const float* __restrict__ k,
                                                    const float* __restrict__ v,
                                                    float* __restrict__ x1)
{
    __shared__ float Ks[128][64];
    __shared__ float Vs[128][64];
    int n = blockIdx.x >> 3, h = blockIdx.x & 7;
    int t = threadIdx.x;
    const float* kb = k + ((size_t)n * 128) * D + h * 64;
    const float* vb = v + ((size_t)n * 128) * D + h * 64;
#pragma unroll
    for (int i = 0; i < 16; ++i) {
        int idx = t + 128 * i;
        int row = idx >> 4, c4 = idx & 15;
        *(float4*)&Ks[row][c4*4] = ld4(kb + (size_t)row * D + c4*4);
        *(float4*)&Vs[row][c4*4] = ld4(vb + (size_t)row * D + c4*4);
    }
    const float* qb = q + ((size_t)(n * 128 + t)) * D + h * 64;
    float4 qv[16];
#pragma unroll
    for (int i = 0; i < 16; ++i) qv[i] = ld4(qb + i*4);
    __syncthreads();

    float mx = -1e30f;
    for (int j = 0; j < 128; ++j) {
        float s = 0.f;
#pragma unroll
        for (int i = 0; i < 16; ++i) {
            float4 kv = ld4(&Ks[j][i*4]);
            s += qv[i].x*kv.x + qv[i].y*kv.y + qv[i].z*kv.z + qv[i].w*kv.w;
        }
        mx = fmaxf(mx, s * 0.125f);
    }
    float4 o[16];
#pragma unroll
    for (int i = 0; i < 16; ++i) o[i] = make_float4(0.f, 0.f, 0.f, 0.f);
    float lsum = 0.f;
    for (int j = 0; j < 128; ++j) {
        float s = 0.f;
#pragma unroll
        for (int i = 0; i < 16; ++i) {
            float4 kv = ld4(&Ks[j][i*4]);
            s += qv[i].x*kv.x + qv[i].y*kv.y + qv[i].z*kv.z + qv[i].w*kv.w;
        }
        float p = expf(s * 0.125f - mx);
        lsum += p;
#pragma unroll
        for (int i = 0; i < 16; ++i) {
            float4 vv = ld4(&Vs[j][i*4]);
            o[i].x += p*vv.x; o[i].y += p*vv.y; o[i].z += p*vv.z; o[i].w += p*vv.w;
        }
    }
    float inv = 1.f / lsum;
    float* xb = x1 + ((size_t)(n * 128 + t)) * D + h * 64;
#pragma unroll
    for (int i = 0; i < 16; ++i) {
        float4 ov = o[i];
        ov.x *= inv; ov.y *= inv; ov.z *= inv; ov.w *= inv;
        *(float4*)(xb + i*4) = ov;
    }
}

// ---------------------------------------------------------------------------
// Attention 2: per (s,b), self-attention over A=16 with q=k=v, 8 heads.
// x1: [A,B,S,D] -> rows x1[a,b,s,:]; x2 same layout.
// ---------------------------------------------------------------------------
__global__ __launch_bounds__(256) void attn2_kernel(const float* __restrict__ x1,
                                                    float* __restrict__ x2)
{
    __shared__ float Xs[16][516];        // padded (+4) to break conflicts
    __shared__ float Sc[8][16][16];
    int m = blockIdx.x;                  // s*16 + b
    int s = m >> 4, b = m & 15;
    int t = threadIdx.x;
#pragma unroll
    for (int i = 0; i < 8; ++i) {
        int f4 = t + 256 * i;            // 0..2047
        int a = f4 >> 7, d4 = f4 & 127;
        float4 vv = ld4(x1 + (((size_t)(a * 16 + b)) * 128 + s) * D + d4*4);
        *(float4*)&Xs[a][d4*4] = vv;
    }
    __syncthreads();
    {
        int h = t >> 5;
        int idx = t & 31;
        int r = idx >> 1;
        int jb = (idx & 1) * 8;
        float4 qv[16];
#pragma unroll
        for (int i = 0; i < 16; ++i) qv[i] = ld4(&Xs[r][h*64 + i*4]);
        for (int j = jb; j < jb + 8; ++j) {
            float sacc = 0.f;
#pragma unroll
            for (int i = 0; i < 16; ++i) {
                float4 kv = ld4(&Xs[j][h*64 + i*4]);
                sacc += qv[i].x*kv.x + qv[i].y*kv.y + qv[i].z*kv.z + qv[i].w*kv.w;
            }
            Sc[h][r][j] = sacc * 0.125f;  // 1/sqrt(64)
        }
    }
    __syncthreads();
    if (t < 128) {
        int h = t >> 4, r = t & 15;
        float* row = &Sc[h][r][0];
        float mx = row[0];
#pragma unroll
        for (int j = 1; j < 16; ++j) mx = fmaxf(mx, row[j]);
        float sum = 0.f;
#pragma unroll
        for (int j = 0; j < 16; ++j) { float e = expf(row[j] - mx); row[j] = e; sum += e; }
        float inv = 1.f / sum;
#pragma unroll
        for (int j = 0; j < 16; ++j) row[j] *= inv;
    }
    __syncthreads();
#pragma unroll
    for (int i = 0; i < 8; ++i) {
        int f4 = t + 256 * i;
        int a = f4 >> 7, d4 = f4 & 127;
        int h = d4 >> 4;
        float4 acc = {0,0,0,0};
#pragma unroll
        for (int j = 0; j < 16; ++j) {
            float wj = Sc[h][a][j];
            float4 vv = ld4(&Xs[j][d4*4]);
            acc.x += wj*vv.x; acc.y += wj*vv.y; acc.z += wj*vv.z; acc.w += wj*vv.w;
        }
        *(float4*)(x2 + (((size_t)(a * 16 + b)) * 128 + s) * D + d4*4) = acc;
    }
}

// ---------------------------------------------------------------------------
// Workspace layout (peak 194.6 MiB, fits 256 MiB):
//   Y  : 256*132*512 fp32 (66 MiB)   -- conv output; later aliased by V, X1
//   Q  : 256*128*512 fp32 (64 MiB)   -- q branch result; later aliased by X2
//   K  : 256*128*512 fp32 (64 MiB)
//   WB : 256*128*5   fp32 (0.63 MiB)
// ---------------------------------------------------------------------------
extern "C" void kernel_launch(void* const* d_in, const int* in_sizes, int n_in,
                              void* d_out, int out_size, void* d_ws, size_t ws_size,
                              hipStream_t stream)
{
    const float* query = (const float*)d_in[0];
    const float* key   = (const float*)d_in[1];
    const float* value = (const float*)d_in[2];
    // d_in[3] = mask (unused by reference)
    const float* padq  = (const float*)d_in[4];
    const float* padk  = (const float*)d_in[5];
    const float* Wq = (const float*)d_in[6];  const float* bq = (const float*)d_in[7];
    const float* Wk = (const float*)d_in[8];  const float* bk = (const float*)d_in[9];
    const float* Wv = (const float*)d_in[10]; const float* bv = (const float*)d_in[11];
    const float* Wo = (const float*)d_in[12]; const float* bo = (const float*)d_in[13];
    float* out = (float*)d_out;

    float* Y  = (float*)d_ws;                         // 17,301,504 floats
    float* Q  = Y + (size_t)NB * T132 * D;            // 16,777,216 floats
    float* K  = Q + (size_t)NB * S * D;               // 16,777,216 floats
    float* WB = K + (size_t)NB * S * D;               //    163,840 floats
    float* V  = Y;                                    // alias: Y dead after k-branch combine
    float* X1 = V;                                    // in-place attn1 (see note)
    float* X2 = Q;                                    // alias: Q dead after attn1

    dim3 blk(256);
    // q projection branch
    gemm_rowgather<<<dim3(33792/64, 8), blk, 0, stream>>>(query, padq, Wq, bq, Y, T132, 4);
    win_weights  <<<8192, blk, 0, stream>>>(Y, WB);
    win_combine  <<<8192, blk, 0, stream>>>(Y, WB, Q);
    // k projection branch
    gemm_rowgather<<<dim3(33792/64, 8), blk, 0, stream>>>(key, padk, Wk, bk, Y, T132, 4);
    win_weights  <<<8192, blk, 0, stream>>>(Y, WB);
    win_combine  <<<8192, blk, 0, stream>>>(Y, WB, K);
    // v projection (overwrites Y space — Y dead now)
    gemm_rowgather<<<dim3(32768/64, 8), blk, 0, stream>>>(value, nullptr, Wv, bv, V, S, 0);
    // attention over S per (n,h); writes X1 in place over V
    attn1_kernel<<<2048, dim3(128), 0, stream>>>(Q, K, V, X1);
    // attention over A per (s,b); writes X2 over Q
    attn2_kernel<<<2048, blk, 0, stream>>>(X1, X2);
    // output projection
    gemm_rowgather<<<dim3(32768/64, 8), blk, 0, stream>>>(X2, nullptr, Wo, bo, out, S, 0);
}

// Round 3
// 1514.145 us; speedup vs baseline: 1.1931x; 1.1931x over previous
//
#include <hip/hip_runtime.h>
#include <math.h>

#define D 512
#define S 128
#define NB 256   // N = A*B
#define T132 132 // S + L - 1

static inline __device__ float4 ld4(const float* p) { return *(const float4*)p; }
static inline __device__ float4 ld4s(const float* p) { return *(const float4*)p; }
static inline __device__ float2 ld2s(const float* p) { return *(const float2*)p; }

// ---------------------------------------------------------------------------
// GEMM: out[m, o] = sum_d src(m)[d] * W[o][d] + bias[o]
// src(m): row gather over concat(pad, x) per n (padRows leading pad rows).
// Tile 64x64, 256 threads, 4x4 acc/thread, k-chunk 16, transposed LDS tiles.
// ---------------------------------------------------------------------------
__global__ __launch_bounds__(256) void gemm_rowgather(
    const float* __restrict__ x, const float* __restrict__ pad,
    const float* __restrict__ W, const float* __restrict__ bias,
    float* __restrict__ out, int rowsPerN, int padRows)
{
    __shared__ float XsT[16][68];
    __shared__ float WsT[16][68];
    const int t  = threadIdx.x;
    const int ty = t >> 4, tx = t & 15;
    const int blockRow = blockIdx.x * 64;
    const int blockCol = blockIdx.y * 64;
    const int lrow = t >> 2;          // 0..63
    const int lk   = (t & 3) * 4;     // 0,4,8,12

    int m = blockRow + lrow;
    int n = m / rowsPerN;
    int r = m - n * rowsPerN;
    const float* src = (r < padRows)
        ? (pad + ((size_t)(n * padRows + r)) * D)
        : (x   + ((size_t)(n * S + (r - padRows))) * D);
    const float* wrow = W + (size_t)(blockCol + lrow) * D;

    float acc[4][4] = {};
    for (int k0 = 0; k0 < D; k0 += 16) {
        float4 xa = ld4(src  + k0 + lk);
        float4 wa = ld4(wrow + k0 + lk);
        __syncthreads();
        XsT[lk+0][lrow] = xa.x; XsT[lk+1][lrow] = xa.y;
        XsT[lk+2][lrow] = xa.z; XsT[lk+3][lrow] = xa.w;
        WsT[lk+0][lrow] = wa.x; WsT[lk+1][lrow] = wa.y;
        WsT[lk+2][lrow] = wa.z; WsT[lk+3][lrow] = wa.w;
        __syncthreads();
#pragma unroll
        for (int kk = 0; kk < 16; ++kk) {
            float4 av = *(const float4*)&XsT[kk][ty * 4];
            float4 bv = *(const float4*)&WsT[kk][tx * 4];
            acc[0][0] += av.x*bv.x; acc[0][1] += av.x*bv.y; acc[0][2] += av.x*bv.z; acc[0][3] += av.x*bv.w;
            acc[1][0] += av.y*bv.x; acc[1][1] += av.y*bv.y; acc[1][2] += av.y*bv.z; acc[1][3] += av.y*bv.w;
            acc[2][0] += av.z*bv.x; acc[2][1] += av.z*bv.y; acc[2][2] += av.z*bv.z; acc[2][3] += av.z*bv.w;
            acc[3][0] += av.w*bv.x; acc[3][1] += av.w*bv.y; acc[3][2] += av.w*bv.z; acc[3][3] += av.w*bv.w;
        }
    }
    float4 bb = ld4(bias + blockCol + tx * 4);
#pragma unroll
    for (int i = 0; i < 4; ++i) {
        float4 o;
        o.x = acc[i][0] + bb.x; o.y = acc[i][1] + bb.y;
        o.z = acc[i][2] + bb.z; o.w = acc[i][3] + bb.w;
        *(float4*)(out + (size_t)(blockRow + ty*4 + i) * D + blockCol + tx*4) = o;
    }
}

// ---------------------------------------------------------------------------
// Window softmax weights: one wave per (n, s). y: [N][132][D].
// ---------------------------------------------------------------------------
__global__ __launch_bounds__(256) void win_weights(const float* __restrict__ y,
                                                   float* __restrict__ wbuf)
{
    int g = blockIdx.x * 256 + threadIdx.x;
    int wv = g >> 6, lane = g & 63;
    int n = wv >> 7, s = wv & 127;
    const float* base = y + ((size_t)(n * T132 + s)) * D;
    float4 c0 = ld4(base + 4*D + lane*4);
    float4 c1 = ld4(base + 4*D + 256 + lane*4);
    float sc[5];
#pragma unroll
    for (int j = 0; j < 5; ++j) {
        float4 a0 = ld4(base + j*D + lane*4);
        float4 a1 = ld4(base + j*D + 256 + lane*4);
        float p = c0.x*a0.x + c0.y*a0.y + c0.z*a0.z + c0.w*a0.w
                + c1.x*a1.x + c1.y*a1.y + c1.z*a1.z + c1.w*a1.w;
#pragma unroll
        for (int off = 1; off < 64; off <<= 1) p += __shfl_xor(p, off);
        sc[j] = p * 0.044194173824159216f;   // 1/sqrt(512)
    }
    if (lane == 0) {
        float mx = sc[0];
#pragma unroll
        for (int j = 1; j < 5; ++j) mx = fmaxf(mx, sc[j]);
        float e[5], sum = 0.f;
#pragma unroll
        for (int j = 0; j < 5; ++j) { e[j] = expf(sc[j] - mx); sum += e[j]; }
        float inv = 1.f / sum;
        float* wp = wbuf + ((size_t)(n * 128 + s)) * 5;
#pragma unroll
        for (int j = 0; j < 5; ++j) wp[j] = e[j] * inv;
    }
}

// ---------------------------------------------------------------------------
// Scrambled window combine (reference's reshape (S,L)->(L,S)):
// out[n,s2,:] = sum_{l2<5} w[n, f/5, f%5] * y[n, f/5 + f%5, :],  f = l2*128+s2
// ---------------------------------------------------------------------------
__global__ __launch_bounds__(256) void win_combine(const float* __restrict__ y,
                                                   const float* __restrict__ wbuf,
                                                   float* __restrict__ outq)
{
    int g = blockIdx.x * 256 + threadIdx.x;
    int wv = g >> 6, lane = g & 63;
    int n = wv >> 7, s2 = wv & 127;
    float4 a0 = {0,0,0,0}, a1 = {0,0,0,0};
#pragma unroll
    for (int l2 = 0; l2 < 5; ++l2) {
        int f = l2 * 128 + s2;
        int sidx = f / 5;
        int l = f - sidx * 5;
        float wt = wbuf[((size_t)(n * 128 + sidx)) * 5 + l];
        const float* r = y + ((size_t)(n * T132 + sidx + l)) * D;
        float4 v0 = ld4(r + lane*4), v1 = ld4(r + 256 + lane*4);
        a0.x += wt*v0.x; a0.y += wt*v0.y; a0.z += wt*v0.z; a0.w += wt*v0.w;
        a1.x += wt*v1.x; a1.y += wt*v1.y; a1.z += wt*v1.z; a1.w += wt*v1.w;
    }
    float* op = outq + ((size_t)(n * 128 + s2)) * D;
    *(float4*)(op + lane*4) = a0;
    *(float4*)(op + 256 + lane*4) = a1;
}

// ---------------------------------------------------------------------------
// Attention 1 (rewritten): per (n,h) block, 512 threads (16x32).
// GEMM1: S = Q*K^T (128x128x64), each thread an 8x4 tile, scores in registers.
// Softmax: shfl_xor reduce across the 32 tx lanes (row direction), exp in regs.
// P -> LDS (float4, contiguous). GEMM2: X = P*V (128x64x128), 8x2 tile.
// LDS: Qs[128][68] (reused for V) + KsT[64][132] + Ps[128][132] = 133 KB.
// All main-loop LDS reads are broadcast (no tx dep) or contiguous (tx-major).
// x1 may alias v: V is fully staged to LDS (and synced) before x1 is written;
// block (n,h) writes only its own (n,h) slice.
// ---------------------------------------------------------------------------
__global__ __launch_bounds__(512) void attn1_kernel(const float* __restrict__ q,
                                                    const float* __restrict__ k,
                                                    const float* __restrict__ v,
                                                    float* __restrict__ x1)
{
    __shared__ float Qs[128 * 68];     // Q rows [r][kd], stride 68; reused for V
    __shared__ float KsT[64 * 132];    // K transposed [kd][j], stride 132
    __shared__ float Ps[128 * 132];    // P rows [r][j], stride 132

    const int n = blockIdx.x >> 3, h = blockIdx.x & 7;
    const int t = threadIdx.x;
    const int ty = t >> 5, tx = t & 31;
    const int r0 = ty * 8;             // 8 score rows per thread
    const int c0 = tx * 4;             // 4 score cols per thread

    const float* qb = q + ((size_t)n * 128) * D + h * 64;
    const float* kb = k + ((size_t)n * 128) * D + h * 64;
    const float* vb = v + ((size_t)n * 128) * D + h * 64;

    // ---- stage Q (row-major) and K (transposed) ----
#pragma unroll
    for (int i = 0; i < 4; ++i) {
        int f4 = t + 512 * i;          // 0..2047
        int row = f4 >> 4, c4 = f4 & 15;
        float4 qv = ld4(qb + (size_t)row * D + c4 * 4);
        *(float4*)&Qs[row * 68 + c4 * 4] = qv;
        float4 kv = ld4(kb + (size_t)row * D + c4 * 4);
        KsT[(c4*4 + 0) * 132 + row] = kv.x;
        KsT[(c4*4 + 1) * 132 + row] = kv.y;
        KsT[(c4*4 + 2) * 132 + row] = kv.z;
        KsT[(c4*4 + 3) * 132 + row] = kv.w;
    }
    __syncthreads();

    // ---- GEMM1: S tile 8x4 in registers ----
    float acc[8][4];
#pragma unroll
    for (int i = 0; i < 8; ++i)
#pragma unroll
        for (int j = 0; j < 4; ++j) acc[i][j] = 0.f;

    for (int kk = 0; kk < 64; kk += 4) {
        float4 bv0 = ld4s(&KsT[(kk+0)*132 + c0]);
        float4 bv1 = ld4s(&KsT[(kk+1)*132 + c0]);
        float4 bv2 = ld4s(&KsT[(kk+2)*132 + c0]);
        float4 bv3 = ld4s(&KsT[(kk+3)*132 + c0]);
#pragma unroll
        for (int i = 0; i < 8; ++i) {
            float4 av = ld4s(&Qs[(r0+i)*68 + kk]);
            acc[i][0] += av.x*bv0.x + av.y*bv1.x + av.z*bv2.x + av.w*bv3.x;
            acc[i][1] += av.x*bv0.y + av.y*bv1.y + av.z*bv2.y + av.w*bv3.y;
            acc[i][2] += av.x*bv0.z + av.y*bv1.z + av.z*bv2.z + av.w*bv3.z;
            acc[i][3] += av.x*bv0.w + av.y*bv1.w + av.z*bv2.w + av.w*bv3.w;
        }
    }

    // ---- softmax over cols (tx direction), exp in regs, P -> LDS ----
    float lrow[8];
#pragma unroll
    for (int i = 0; i < 8; ++i) {
        float m = fmaxf(fmaxf(acc[i][0], acc[i][1]), fmaxf(acc[i][2], acc[i][3]));
        m *= 0.125f;
#pragma unroll
        for (int off = 1; off < 32; off <<= 1) m = fmaxf(m, __shfl_xor(m, off));
        float4 p;
        p.x = __expf(acc[i][0]*0.125f - m);
        p.y = __expf(acc[i][1]*0.125f - m);
        p.z = __expf(acc[i][2]*0.125f - m);
        p.w = __expf(acc[i][3]*0.125f - m);
        float l = p.x + p.y + p.z + p.w;
#pragma unroll
        for (int off = 1; off < 32; off <<= 1) l += __shfl_xor(l, off);
        lrow[i] = l;
        *(float4*)&Ps[(r0+i)*132 + c0] = p;
    }

    // ---- stage V into Qs buffer (Q dead) ----
    __syncthreads();
#pragma unroll
    for (int i = 0; i < 4; ++i) {
        int f4 = t + 512 * i;
        int row = f4 >> 4, c4 = f4 & 15;
        float4 vv = ld4(vb + (size_t)row * D + c4 * 4);
        *(float4*)&Qs[row * 68 + c4 * 4] = vv;
    }
    __syncthreads();

    // ---- GEMM2: X = P*V, thread tile 8 rows x 2 cols ----
    const int c2 = tx * 2;
    float xacc[8][2];
#pragma unroll
    for (int i = 0; i < 8; ++i) { xacc[i][0] = 0.f; xacc[i][1] = 0.f; }

    for (int kk = 0; kk < 128; kk += 4) {
        float2 vv0 = ld2s(&Qs[(kk+0)*68 + c2]);
        float2 vv1 = ld2s(&Qs[(kk+1)*68 + c2]);
        float2 vv2 = ld2s(&Qs[(kk+2)*68 + c2]);
        float2 vv3 = ld2s(&Qs[(kk+3)*68 + c2]);
#pragma unroll
        for (int i = 0; i < 8; ++i) {
            float4 pv = ld4s(&Ps[(r0+i)*132 + kk]);
            xacc[i][0] += pv.x*vv0.x + pv.y*vv1.x + pv.z*vv2.x + pv.w*vv3.x;
            xacc[i][1] += pv.x*vv0.y + pv.y*vv1.y + pv.z*vv2.y + pv.w*vv3.y;
        }
    }

    // ---- epilogue: normalize and store ----
#pragma unroll
    for (int i = 0; i < 8; ++i) {
        float inv = 1.f / lrow[i];
        float2 o; o.x = xacc[i][0] * inv; o.y = xacc[i][1] * inv;
        *(float2*)(x1 + ((size_t)(n * 128 + r0 + i)) * D + h * 64 + c2) = o;
    }
}

// ---------------------------------------------------------------------------
// Attention 2: per (s,b), self-attention over A=16 with q=k=v, 8 heads.
// ---------------------------------------------------------------------------
__global__ __launch_bounds__(256) void attn2_kernel(const float* __restrict__ x1,
                                                    float* __restrict__ x2)
{
    __shared__ float Xs[16][516];        // padded (+4) to break conflicts
    __shared__ float Sc[8][16][16];
    int m = blockIdx.x;                  // s*16 + b
    int s = m >> 4, b = m & 15;
    int t = threadIdx.x;
#pragma unroll
    for (int i = 0; i < 8; ++i) {
        int f4 = t + 256 * i;            // 0..2047
        int a = f4 >> 7, d4 = f4 & 127;
        float4 vv = ld4(x1 + (((size_t)(a * 16 + b)) * 128 + s) * D + d4*4);
        *(float4*)&Xs[a][d4*4] = vv;
    }
    __syncthreads();
    {
        int h = t >> 5;
        int idx = t & 31;
        int r = idx >> 1;
        int jb = (idx & 1) * 8;
        float4 qv[16];
#pragma unroll
        for (int i = 0; i < 16; ++i) qv[i] = ld4(&Xs[r][h*64 + i*4]);
        for (int j = jb; j < jb + 8; ++j) {
            float sacc = 0.f;
#pragma unroll
            for (int i = 0; i < 16; ++i) {
                float4 kv = ld4(&Xs[j][h*64 + i*4]);
                sacc += qv[i].x*kv.x + qv[i].y*kv.y + qv[i].z*kv.z + qv[i].w*kv.w;
            }
            Sc[h][r][j] = sacc * 0.125f;  // 1/sqrt(64)
        }
    }
    __syncthreads();
    if (t < 128) {
        int h = t >> 4, r = t & 15;
        float* row = &Sc[h][r][0];
        float mx = row[0];
#pragma unroll
        for (int j = 1; j < 16; ++j) mx = fmaxf(mx, row[j]);
        float sum = 0.f;
#pragma unroll
        for (int j = 0; j < 16; ++j) { float e = expf(row[j] - mx); row[j] = e; sum += e; }
        float inv = 1.f / sum;
#pragma unroll
        for (int j = 0; j < 16; ++j) row[j] *= inv;
    }
    __syncthreads();
#pragma unroll
    for (int i = 0; i < 8; ++i) {
        int f4 = t + 256 * i;
        int a = f4 >> 7, d4 = f4 & 127;
        int h = d4 >> 4;
        float4 acc = {0,0,0,0};
#pragma unroll
        for (int j = 0; j < 16; ++j) {
            float wj = Sc[h][a][j];
            float4 vv = ld4(&Xs[j][d4*4]);
            acc.x += wj*vv.x; acc.y += wj*vv.y; acc.z += wj*vv.z; acc.w += wj*vv.w;
        }
        *(float4*)(x2 + (((size_t)(a * 16 + b)) * 128 + s) * D + d4*4) = acc;
    }
}

// ---------------------------------------------------------------------------
// Workspace layout (peak 194.6 MiB):
//   Y[66 MiB] (aliased later by V, X1) | Q[64 MiB] (aliased by X2) | K[64 MiB]
//   | WB[0.63 MiB]
// ---------------------------------------------------------------------------
extern "C" void kernel_launch(void* const* d_in, const int* in_sizes, int n_in,
                              void* d_out, int out_size, void* d_ws, size_t ws_size,
                              hipStream_t stream)
{
    const float* query = (const float*)d_in[0];
    const float* key   = (const float*)d_in[1];
    const float* value = (const float*)d_in[2];
    // d_in[3] = mask (unused by reference)
    const float* padq  = (const float*)d_in[4];
    const float* padk  = (const float*)d_in[5];
    const float* Wq = (const float*)d_in[6];  const float* bq = (const float*)d_in[7];
    const float* Wk = (const float*)d_in[8];  const float* bk = (const float*)d_in[9];
    const float* Wv = (const float*)d_in[10]; const float* bv = (const float*)d_in[11];
    const float* Wo = (const float*)d_in[12]; const float* bo = (const float*)d_in[13];
    float* out = (float*)d_out;

    float* Y  = (float*)d_ws;                         // 17,301,504 floats
    float* Q  = Y + (size_t)NB * T132 * D;            // 16,777,216 floats
    float* K  = Q + (size_t)NB * S * D;               // 16,777,216 floats
    float* WB = K + (size_t)NB * S * D;               //    163,840 floats
    float* V  = Y;                                    // alias: Y dead after k-branch combine
    float* X1 = V;                                    // in-place attn1 (see note)
    float* X2 = Q;                                    // alias: Q dead after attn1

    dim3 blk(256);
    // q projection branch
    gemm_rowgather<<<dim3(33792/64, 8), blk, 0, stream>>>(query, padq, Wq, bq, Y, T132, 4);
    win_weights  <<<8192, blk, 0, stream>>>(Y, WB);
    win_combine  <<<8192, blk, 0, stream>>>(Y, WB, Q);
    // k projection branch
    gemm_rowgather<<<dim3(33792/64, 8), blk, 0, stream>>>(key, padk, Wk, bk, Y, T132, 4);
    win_weights  <<<8192, blk, 0, stream>>>(Y, WB);
    win_combine  <<<8192, blk, 0, stream>>>(Y, WB, K);
    // v projection (overwrites Y space — Y dead now)
    gemm_rowgather<<<dim3(32768/64, 8), blk, 0, stream>>>(value, nullptr, Wv, bv, V, S, 0);
    // attention over S per (n,h); writes X1 in place over V
    attn1_kernel<<<2048, dim3(512), 0, stream>>>(Q, K, V, X1);
    // attention over A per (s,b); writes X2 over Q
    attn2_kernel<<<2048, blk, 0, stream>>>(X1, X2);
    // output projection
    gemm_rowgather<<<dim3(32768/64, 8), blk, 0, stream>>>(X2, nullptr, Wo, bo, out, S, 0);
}

// Round 4
// 964.799 us; speedup vs baseline: 1.8724x; 1.5694x over previous
//
#include <hip/hip_runtime.h>
#include <math.h>

#define D 512
#define S 128
#define NB 256   // N = A*B
#define T132 132 // S + L - 1

typedef short s16x8 __attribute__((ext_vector_type(8)));   // 8 bf16 (4 VGPRs)
typedef float f32x4 __attribute__((ext_vector_type(4)));
typedef unsigned short ushort;

static inline __device__ float4 ld4(const float* p) { return *(const float4*)p; }
static inline __device__ float4 ld4s(const float* p) { return *(const float4*)p; }
static inline __device__ float2 ld2s(const float* p) { return *(const float2*)p; }

// async global->LDS, 16B per lane; lp must be wave-uniform base, lane l lands at lp + 16*l
#define GLOAD_LDS16(gp, lp) __builtin_amdgcn_global_load_lds( \
    (const __attribute__((address_space(1))) unsigned int*)(const void*)(gp), \
    (__attribute__((address_space(3))) unsigned int*)(void*)(lp), 16, 0, 0)

static inline __device__ ushort bf16_rtn(float f) {
    unsigned u = __float_as_uint(f);
    unsigned r = u + 0x7FFFu + ((u >> 16) & 1u);
    return (ushort)(r >> 16);
}

// ---------------------------------------------------------------------------
// Split fp32 rows (with optional per-n leading pad rows) into bf16 hi/lo.
// Row m: n = m/rowsPerN, r = m%rowsPerN; src = pad row if r<padRows else x row.
// Each thread converts 8 floats -> 8 hi + 8 lo bf16 (16B stores).
// grid.x = rows/4, block 256.
// ---------------------------------------------------------------------------
__global__ __launch_bounds__(256) void split_rows(
    const float* __restrict__ x, const float* __restrict__ pad,
    ushort* __restrict__ hi, ushort* __restrict__ lo,
    int rowsPerN, int padRows)
{
    int id  = blockIdx.x * 256 + threadIdx.x;
    int row = id >> 6, c8 = (id & 63) * 8;
    int n = row / rowsPerN, r = row - n * rowsPerN;
    const float* src = (r < padRows)
        ? (pad + ((size_t)(n * padRows + r)) * D + c8)
        : (x   + ((size_t)(n * (rowsPerN - padRows) + (r - padRows))) * D + c8);
    float4 f0 = ld4(src), f1 = ld4(src + 4);
    float v[8] = {f0.x,f0.y,f0.z,f0.w,f1.x,f1.y,f1.z,f1.w};
    ushort h[8], l[8];
#pragma unroll
    for (int i = 0; i < 8; ++i) {
        h[i] = bf16_rtn(v[i]);
        float hf = __uint_as_float(((unsigned)h[i]) << 16);
        l[i] = bf16_rtn(v[i] - hf);
    }
    size_t o = (size_t)row * D + c8;
#pragma unroll
    for (int i = 0; i < 4; ++i) {
        ((ushort2*)(hi + o))[i] = make_ushort2(h[2*i], h[2*i+1]);
        ((ushort2*)(lo + o))[i] = make_ushort2(l[2*i], l[2*i+1]);
    }
}

// ---------------------------------------------------------------------------
// Split-bf16 MFMA GEMM: out[m][o] = sum_d A[m][d]*W[o][d] + bias[o]
// A ~ Ahi+Alo, W ~ Bhi+Blo (bf16). 3 MFMA terms: hh + hl + lh.
// Tile 128x128, BK=32, 256 thr = 4 waves (2x2), each wave 64x64 via 4x4
// mfma_f32_16x16x32_bf16. LDS in fragment order: chunk (buf,subtile) is
// 64 lanes x 16 B, matching both global_load_lds lane order and ds_read_b128
// fragment reads (conflict-free).
// grid: (M/128, 4). M multiple of 128. K = N = 512.
// ---------------------------------------------------------------------------
__global__ __launch_bounds__(256, 2) void gemm_mfma_split(
    const ushort* __restrict__ Ahi, const ushort* __restrict__ Alo,
    const ushort* __restrict__ Bhi, const ushort* __restrict__ Blo,
    const float* __restrict__ bias, float* __restrict__ out, int M)
{
    __shared__ ushort lds[32 * 512];   // 32 chunks x (64 lanes x 8 bf16) = 32 KB
    const int t = threadIdx.x;
    const int wave = t >> 6, lane = t & 63;
    const int wm = wave >> 1, wn = wave & 1;
    const int blockRow = blockIdx.x * 128;
    const int blockCol = blockIdx.y * 128;

    // staging source for this wave's buffer (wave = buffer index)
    const ushort* gsrc = (wave == 0) ? Ahi : (wave == 1) ? Alo : (wave == 2) ? Bhi : Blo;
    const int rowBase = (wave < 2) ? blockRow : blockCol;
    const int srow = rowBase + (lane & 15);      // +t*16 per chunk
    const int scol = (lane >> 4) * 8;

    f32x4 acc[4][4];
#pragma unroll
    for (int i = 0; i < 4; ++i)
#pragma unroll
        for (int j = 0; j < 4; ++j) acc[i][j] = (f32x4){0.f,0.f,0.f,0.f};

    for (int k0 = 0; k0 < 512; k0 += 32) {
        __syncthreads();
#pragma unroll
        for (int st = 0; st < 8; ++st) {
            const ushort* gp = gsrc + (size_t)(srow + st * 16) * 512 + k0 + scol;
            GLOAD_LDS16(gp, &lds[(wave * 8 + st) * 512]);
        }
        __syncthreads();

        s16x8 ah[4], al[4], bh[4], bl[4];
#pragma unroll
        for (int i = 0; i < 4; ++i) {
            ah[i] = *(const s16x8*)&lds[( 0 + wm * 4 + i) * 512 + lane * 8];
            al[i] = *(const s16x8*)&lds[( 8 + wm * 4 + i) * 512 + lane * 8];
            bh[i] = *(const s16x8*)&lds[(16 + wn * 4 + i) * 512 + lane * 8];
            bl[i] = *(const s16x8*)&lds[(24 + wn * 4 + i) * 512 + lane * 8];
        }
#pragma unroll
        for (int i = 0; i < 4; ++i)
#pragma unroll
            for (int j = 0; j < 4; ++j) {
                acc[i][j] = __builtin_amdgcn_mfma_f32_16x16x32_bf16(ah[i], bh[j], acc[i][j], 0, 0, 0);
                acc[i][j] = __builtin_amdgcn_mfma_f32_16x16x32_bf16(ah[i], bl[j], acc[i][j], 0, 0, 0);
                acc[i][j] = __builtin_amdgcn_mfma_f32_16x16x32_bf16(al[i], bh[j], acc[i][j], 0, 0, 0);
            }
    }

    // epilogue: C/D layout col=lane&15, row=(lane>>4)*4+reg
#pragma unroll
    for (int j = 0; j < 4; ++j) {
        int col = blockCol + (wn * 4 + j) * 16 + (lane & 15);
        float bb = bias[col];
#pragma unroll
        for (int i = 0; i < 4; ++i) {
            int row0 = blockRow + (wm * 4 + i) * 16 + (lane >> 4) * 4;
#pragma unroll
            for (int r = 0; r < 4; ++r)
                out[(size_t)(row0 + r) * 512 + col] = acc[i][j][r] + bb;
        }
    }
}

// ---------------------------------------------------------------------------
// Window softmax weights: one wave per (n, s). y: [N][132][D].
// ---------------------------------------------------------------------------
__global__ __launch_bounds__(256) void win_weights(const float* __restrict__ y,
                                                   float* __restrict__ wbuf)
{
    int g = blockIdx.x * 256 + threadIdx.x;
    int wv = g >> 6, lane = g & 63;
    int n = wv >> 7, s = wv & 127;
    const float* base = y + ((size_t)(n * T132 + s)) * D;
    float4 c0 = ld4(base + 4*D + lane*4);
    float4 c1 = ld4(base + 4*D + 256 + lane*4);
    float sc[5];
#pragma unroll
    for (int j = 0; j < 5; ++j) {
        float4 a0 = ld4(base + j*D + lane*4);
        float4 a1 = ld4(base + j*D + 256 + lane*4);
        float p = c0.x*a0.x + c0.y*a0.y + c0.z*a0.z + c0.w*a0.w
                + c1.x*a1.x + c1.y*a1.y + c1.z*a1.z + c1.w*a1.w;
#pragma unroll
        for (int off = 1; off < 64; off <<= 1) p += __shfl_xor(p, off);
        sc[j] = p * 0.044194173824159216f;   // 1/sqrt(512)
    }
    if (lane == 0) {
        float mx = sc[0];
#pragma unroll
        for (int j = 1; j < 5; ++j) mx = fmaxf(mx, sc[j]);
        float e[5], sum = 0.f;
#pragma unroll
        for (int j = 0; j < 5; ++j) { e[j] = expf(sc[j] - mx); sum += e[j]; }
        float inv = 1.f / sum;
        float* wp = wbuf + ((size_t)(n * 128 + s)) * 5;
#pragma unroll
        for (int j = 0; j < 5; ++j) wp[j] = e[j] * inv;
    }
}

// ---------------------------------------------------------------------------
// Scrambled window combine (reference's reshape (S,L)->(L,S)):
// out[n,s2,:] = sum_{l2<5} w[n, f/5, f%5] * y[n, f/5 + f%5, :],  f = l2*128+s2
// ---------------------------------------------------------------------------
__global__ __launch_bounds__(256) void win_combine(const float* __restrict__ y,
                                                   const float* __restrict__ wbuf,
                                                   float* __restrict__ outq)
{
    int g = blockIdx.x * 256 + threadIdx.x;
    int wv = g >> 6, lane = g & 63;
    int n = wv >> 7, s2 = wv & 127;
    float4 a0 = {0,0,0,0}, a1 = {0,0,0,0};
#pragma unroll
    for (int l2 = 0; l2 < 5; ++l2) {
        int f = l2 * 128 + s2;
        int sidx = f / 5;
        int l = f - sidx * 5;
        float wt = wbuf[((size_t)(n * 128 + sidx)) * 5 + l];
        const float* r = y + ((size_t)(n * T132 + sidx + l)) * D;
        float4 v0 = ld4(r + lane*4), v1 = ld4(r + 256 + lane*4);
        a0.x += wt*v0.x; a0.y += wt*v0.y; a0.z += wt*v0.z; a0.w += wt*v0.w;
        a1.x += wt*v1.x; a1.y += wt*v1.y; a1.z += wt*v1.z; a1.w += wt*v1.w;
    }
    float* op = outq + ((size_t)(n * 128 + s2)) * D;
    *(float4*)(op + lane*4) = a0;
    *(float4*)(op + 256 + lane*4) = a1;
}

// ---------------------------------------------------------------------------
// Attention 1: per (n,h) block, 512 threads (16x32). Scores in registers,
// shfl softmax, P->LDS, then X=P*V. x1 may alias v (V staged before write).
// ---------------------------------------------------------------------------
__global__ __launch_bounds__(512) void attn1_kernel(const float* __restrict__ q,
                                                    const float* __restrict__ k,
                                                    const float* __restrict__ v,
                                                    float* __restrict__ x1)
{
    __shared__ float Qs[128 * 68];     // Q rows [r][kd], stride 68; reused for V
    __shared__ float KsT[64 * 132];    // K transposed [kd][j], stride 132
    __shared__ float Ps[128 * 132];    // P rows [r][j], stride 132

    const int n = blockIdx.x >> 3, h = blockIdx.x & 7;
    const int t = threadIdx.x;
    const int ty = t >> 5, tx = t & 31;
    const int r0 = ty * 8;
    const int c0 = tx * 4;

    const float* qb = q + ((size_t)n * 128) * D + h * 64;
    const float* kb = k + ((size_t)n * 128) * D + h * 64;
    const float* vb = v + ((size_t)n * 128) * D + h * 64;

#pragma unroll
    for (int i = 0; i < 4; ++i) {
        int f4 = t + 512 * i;
        int row = f4 >> 4, c4 = f4 & 15;
        float4 qv = ld4(qb + (size_t)row * D + c4 * 4);
        *(float4*)&Qs[row * 68 + c4 * 4] = qv;
        float4 kv = ld4(kb + (size_t)row * D + c4 * 4);
        KsT[(c4*4 + 0) * 132 + row] = kv.x;
        KsT[(c4*4 + 1) * 132 + row] = kv.y;
        KsT[(c4*4 + 2) * 132 + row] = kv.z;
        KsT[(c4*4 + 3) * 132 + row] = kv.w;
    }
    __syncthreads();

    float acc[8][4];
#pragma unroll
    for (int i = 0; i < 8; ++i)
#pragma unroll
        for (int j = 0; j < 4; ++j) acc[i][j] = 0.f;

    for (int kk = 0; kk < 64; kk += 4) {
        float4 bv0 = ld4s(&KsT[(kk+0)*132 + c0]);
        float4 bv1 = ld4s(&KsT[(kk+1)*132 + c0]);
        float4 bv2 = ld4s(&KsT[(kk+2)*132 + c0]);
        float4 bv3 = ld4s(&KsT[(kk+3)*132 + c0]);
#pragma unroll
        for (int i = 0; i < 8; ++i) {
            float4 av = ld4s(&Qs[(r0+i)*68 + kk]);
            acc[i][0] += av.x*bv0.x + av.y*bv1.x + av.z*bv2.x + av.w*bv3.x;
            acc[i][1] += av.x*bv0.y + av.y*bv1.y + av.z*bv2.y + av.w*bv3.y;
            acc[i][2] += av.x*bv0.z + av.y*bv1.z + av.z*bv2.z + av.w*bv3.z;
            acc[i][3] += av.x*bv0.w + av.y*bv1.w + av.z*bv2.w + av.w*bv3.w;
        }
    }

    float lrow[8];
#pragma unroll
    for (int i = 0; i < 8; ++i) {
        float m = fmaxf(fmaxf(acc[i][0], acc[i][1]), fmaxf(acc[i][2], acc[i][3]));
        m *= 0.125f;
#pragma unroll
        for (int off = 1; off < 32; off <<= 1) m = fmaxf(m, __shfl_xor(m, off));
        float4 p;
        p.x = __expf(acc[i][0]*0.125f - m);
        p.y = __expf(acc[i][1]*0.125f - m);
        p.z = __expf(acc[i][2]*0.125f - m);
        p.w = __expf(acc[i][3]*0.125f - m);
        float l = p.x + p.y + p.z + p.w;
#pragma unroll
        for (int off = 1; off < 32; off <<= 1) l += __shfl_xor(l, off);
        lrow[i] = l;
        *(float4*)&Ps[(r0+i)*132 + c0] = p;
    }

    __syncthreads();
#pragma unroll
    for (int i = 0; i < 4; ++i) {
        int f4 = t + 512 * i;
        int row = f4 >> 4, c4 = f4 & 15;
        float4 vv = ld4(vb + (size_t)row * D + c4 * 4);
        *(float4*)&Qs[row * 68 + c4 * 4] = vv;
    }
    __syncthreads();

    const int c2 = tx * 2;
    float xacc[8][2];
#pragma unroll
    for (int i = 0; i < 8; ++i) { xacc[i][0] = 0.f; xacc[i][1] = 0.f; }

    for (int kk = 0; kk < 128; kk += 4) {
        float2 vv0 = ld2s(&Qs[(kk+0)*68 + c2]);
        float2 vv1 = ld2s(&Qs[(kk+1)*68 + c2]);
        float2 vv2 = ld2s(&Qs[(kk+2)*68 + c2]);
        float2 vv3 = ld2s(&Qs[(kk+3)*68 + c2]);
#pragma unroll
        for (int i = 0; i < 8; ++i) {
            float4 pv = ld4s(&Ps[(r0+i)*132 + kk]);
            xacc[i][0] += pv.x*vv0.x + pv.y*vv1.x + pv.z*vv2.x + pv.w*vv3.x;
            xacc[i][1] += pv.x*vv0.y + pv.y*vv1.y + pv.z*vv2.y + pv.w*vv3.y;
        }
    }

#pragma unroll
    for (int i = 0; i < 8; ++i) {
        float inv = 1.f / lrow[i];
        float2 o; o.x = xacc[i][0] * inv; o.y = xacc[i][1] * inv;
        *(float2*)(x1 + ((size_t)(n * 128 + r0 + i)) * D + h * 64 + c2) = o;
    }
}

// ---------------------------------------------------------------------------
// Attention 2: per (s,b), self-attention over A=16 with q=k=v, 8 heads.
// ---------------------------------------------------------------------------
__global__ __launch_bounds__(256) void attn2_kernel(const float* __restrict__ x1,
                                                    float* __restrict__ x2)
{
    __shared__ float Xs[16][516];
    __shared__ float Sc[8][16][16];
    int m = blockIdx.x;
    int s = m >> 4, b = m & 15;
    int t = threadIdx.x;
#pragma unroll
    for (int i = 0; i < 8; ++i) {
        int f4 = t + 256 * i;
        int a = f4 >> 7, d4 = f4 & 127;
        float4 vv = ld4(x1 + (((size_t)(a * 16 + b)) * 128 + s) * D + d4*4);
        *(float4*)&Xs[a][d4*4] = vv;
    }
    __syncthreads();
    {
        int h = t >> 5;
        int idx = t & 31;
        int r = idx >> 1;
        int jb = (idx & 1) * 8;
        float4 qv[16];
#pragma unroll
        for (int i = 0; i < 16; ++i) qv[i] = ld4(&Xs[r][h*64 + i*4]);
        for (int j = jb; j < jb + 8; ++j) {
            float sacc = 0.f;
#pragma unroll
            for (int i = 0; i < 16; ++i) {
                float4 kv = ld4(&Xs[j][h*64 + i*4]);
                sacc += qv[i].x*kv.x + qv[i].y*kv.y + qv[i].z*kv.z + qv[i].w*kv.w;
            }
            Sc[h][r][j] = sacc * 0.125f;
        }
    }
    __syncthreads();
    if (t < 128) {
        int h = t >> 4, r = t & 15;
        float* row = &Sc[h][r][0];
        float mx = row[0];
#pragma unroll
        for (int j = 1; j < 16; ++j) mx = fmaxf(mx, row[j]);
        float sum = 0.f;
#pragma unroll
        for (int j = 0; j < 16; ++j) { float e = expf(row[j] - mx); row[j] = e; sum += e; }
        float inv = 1.f / sum;
#pragma unroll
        for (int j = 0; j < 16; ++j) row[j] *= inv;
    }
    __syncthreads();
#pragma unroll
    for (int i = 0; i < 8; ++i) {
        int f4 = t + 256 * i;
        int a = f4 >> 7, d4 = f4 & 127;
        int h = d4 >> 4;
        float4 acc = {0,0,0,0};
#pragma unroll
        for (int j = 0; j < 16; ++j) {
            float wj = Sc[h][a][j];
            float4 vv = ld4(&Xs[j][d4*4]);
            acc.x += wj*vv.x; acc.y += wj*vv.y; acc.z += wj*vv.z; acc.w += wj*vv.w;
        }
        *(float4*)(x2 + (((size_t)(a * 16 + b)) * 128 + s) * D + d4*4) = acc;
    }
}

// ---------------------------------------------------------------------------
// Workspace (float offsets), peak ~240 MB:
//  P0 [0)            66 MiB : Y / V / X1
//  P1 [17301504)     64 MiB : Hq(bf16) -> Q / X2
//  P2 [34078720)     64 MiB : Lq(bf16) -> Hk(bf16) -> K
//  WB [50855936)    0.6 MiB : window weights
//  Wh [51019776)    0.5 MiB : W hi (bf16)
//  Wl [51150848)    0.5 MiB : W lo (bf16)
//  P5 [51281920)     33 MiB : Lk -> v/out split halves (hi+lo)
// ---------------------------------------------------------------------------
extern "C" void kernel_launch(void* const* d_in, const int* in_sizes, int n_in,
                              void* d_out, int out_size, void* d_ws, size_t ws_size,
                              hipStream_t stream)
{
    const float* query = (const float*)d_in[0];
    const float* key   = (const float*)d_in[1];
    const float* value = (const float*)d_in[2];
    // d_in[3] = mask (unused)
    const float* padq  = (const float*)d_in[4];
    const float* padk  = (const float*)d_in[5];
    const float* Wq = (const float*)d_in[6];  const float* bq = (const float*)d_in[7];
    const float* Wk = (const float*)d_in[8];  const float* bk = (const float*)d_in[9];
    const float* Wv = (const float*)d_in[10]; const float* bv = (const float*)d_in[11];
    const float* Wo = (const float*)d_in[12]; const float* bo = (const float*)d_in[13];
    float* out = (float*)d_out;
    float* W   = (float*)d_ws;

    float* Y   = W;                         // P0
    float* Q   = W + 17301504;              // P1
    float* K   = W + 34078720;              // P2
    float* WB  = W + 50855936;
    ushort* Whi = (ushort*)(W + 51019776);
    ushort* Wlo = (ushort*)(W + 51150848);
    float* P5  = W + 51281920;
    float* V   = Y;
    float* X1  = V;
    float* X2  = Q;

    ushort* Hq = (ushort*)Q;                // branch A-splits (33 MB each)
    ushort* Lq = (ushort*)K;
    ushort* Hk = (ushort*)K;
    ushort* Lk = (ushort*)P5;
    ushort* Hh = (ushort*)P5;               // half splits for v/out (16 MB each)
    ushort* Lh = Hh + (size_t)16384 * 512;

    dim3 blk(256);
    const int Mbr = NB * T132;              // 33792
    const int Mh  = 16384;

    // ---- q branch ----
    split_rows<<<Mbr/4, blk, 0, stream>>>(query, padq, Hq, Lq, T132, 4);
    split_rows<<<128,   blk, 0, stream>>>(Wq, nullptr, Whi, Wlo, 512, 0);
    gemm_mfma_split<<<dim3(Mbr/128, 4), blk, 0, stream>>>(Hq, Lq, Whi, Wlo, bq, Y, Mbr);
    win_weights<<<8192, blk, 0, stream>>>(Y, WB);
    win_combine<<<8192, blk, 0, stream>>>(Y, WB, Q);      // overwrites Hq (dead)
    // ---- k branch ----
    split_rows<<<Mbr/4, blk, 0, stream>>>(key, padk, Hk, Lk, T132, 4);
    split_rows<<<128,   blk, 0, stream>>>(Wk, nullptr, Whi, Wlo, 512, 0);
    gemm_mfma_split<<<dim3(Mbr/128, 4), blk, 0, stream>>>(Hk, Lk, Whi, Wlo, bk, Y, Mbr);
    win_weights<<<8192, blk, 0, stream>>>(Y, WB);
    win_combine<<<8192, blk, 0, stream>>>(Y, WB, K);      // overwrites Hk (dead)
    // ---- v projection (two M-halves to bound workspace) ----
    split_rows<<<128, blk, 0, stream>>>(Wv, nullptr, Whi, Wlo, 512, 0);
    for (int h = 0; h < 2; ++h) {
        split_rows<<<Mh/4, blk, 0, stream>>>(value + (size_t)h*Mh*512, nullptr, Hh, Lh, 128, 0);
        gemm_mfma_split<<<dim3(Mh/128, 4), blk, 0, stream>>>(Hh, Lh, Whi, Wlo, bv,
                                                             V + (size_t)h*Mh*512, Mh);
    }
    // ---- attention over S; X1 in place over V ----
    attn1_kernel<<<2048, dim3(512), 0, stream>>>(Q, K, V, X1);
    // ---- attention over A ----
    attn2_kernel<<<2048, blk, 0, stream>>>(X1, X2);
    // ---- output projection (two halves) ----
    split_rows<<<128, blk, 0, stream>>>(Wo, nullptr, Whi, Wlo, 512, 0);
    for (int h = 0; h < 2; ++h) {
        split_rows<<<Mh/4, blk, 0, stream>>>(X2 + (size_t)h*Mh*512, nullptr, Hh, Lh, 128, 0);
        gemm_mfma_split<<<dim3(Mh/128, 4), blk, 0, stream>>>(Hh, Lh, Whi, Wlo, bo,
                                                             out + (size_t)h*Mh*512, Mh);
    }
}